// Round 1
// baseline (1394.120 us; speedup 1.0000x reference)
//
#include <hip/hip_runtime.h>

#define NROWS 131072
#define KCODES 1024
#define DDIM 256
#define BN 64
#define NBLK (NROWS / BN)   // 2048
#define ZS 260              // padded z_lds row stride (floats); 16B-aligned rows, breaks bank aliasing
#define CTS 256             // ct row stride (floats), layout ct[d][code]
#define BKC 256             // codes per k0 chunk
#define COMMIT 0.25

// Prevent -ffp-contract=fast from fusing x*x into the following add
// (numpy rounds the product array first, then pairwise-sums).
__device__ __forceinline__ float opaque(float x) {
    asm volatile("" : "+v"(x));
    return x;
}

__device__ __forceinline__ float elem4(const float4& v, int l) {
    switch (l) {
        case 0:  return v.x;
        case 1:  return v.y;
        case 2:  return v.z;
        default: return v.w;
    }
}

// numpy pairwise_sum of squares over 256 contiguous elements:
// split 128+128; each half: 8 accumulators r[j] = sum of x[j], x[j+8], ... (16 terms, in order),
// combined as ((r0+r1)+(r2+r3))+((r4+r5)+(r6+r7)); halves added last.
template <typename LD>
__device__ __forceinline__ float pairwise256_sq(LD ld) {
    float tt[2];
#pragma unroll
    for (int h = 0; h < 2; ++h) {
        float r[8];
#pragma unroll
        for (int j = 0; j < 8; ++j) {
            float e = ld(h * 128 + j);
            float p = e * e;
            p = opaque(p);
            r[j] = p;
        }
#pragma unroll
        for (int i = 1; i < 16; ++i) {
#pragma unroll
            for (int j = 0; j < 8; ++j) {
                float e = ld(h * 128 + i * 8 + j);
                float p = e * e;
                p = opaque(p);
                r[j] += p;
            }
        }
        tt[h] = ((r[0] + r[1]) + (r[2] + r[3])) + ((r[4] + r[5]) + (r[6] + r[7]));
    }
    return tt[0] + tt[1];
}

__global__ void cnorm_k(const float* __restrict__ emb, float* __restrict__ cn) {
    int code = blockIdx.x * blockDim.x + threadIdx.x;
    if (code >= KCODES) return;
    const float* x = emb + (size_t)code * DDIM;
    cn[code] = pairwise256_sq([&](int i) { return x[i]; });
}

__global__ __launch_bounds__(512, 2) void vq_main(
    const float* __restrict__ z_e, const float* __restrict__ emb,
    const float* __restrict__ cn_g, float* __restrict__ out_zq,
    float* __restrict__ out_idx, double* __restrict__ ws_part) {
    __shared__ float z_lds[BN * ZS];   // 66560 B
    __shared__ float ct[64 * CTS];     // 65536 B, reused as argmin-reduce scratch
    __shared__ float cn_l[KCODES];     // 4 KB
    __shared__ float zn_l[BN];
    __shared__ int winner[BN];
    __shared__ double wsum[8];

    const int tid = threadIdx.x;
    const int bid = blockIdx.x;
    const size_t row0 = (size_t)bid * BN;

    // ---- stage z tile (64 x 256) -> LDS (row stride ZS), plus c_norm table ----
    {
        const float4* src = (const float4*)(z_e + row0 * DDIM);
#pragma unroll
        for (int q = 0; q < 8; ++q) {
            int g = q * 512 + tid;  // float4 index 0..4095, coalesced
            float4 v = src[g];
            int r = g >> 6, c4 = g & 63;
            *(float4*)&z_lds[r * ZS + c4 * 4] = v;
        }
        for (int i = tid; i < KCODES; i += 512) cn_l[i] = cn_g[i];
    }
    __syncthreads();

    // ---- z_norm per row (np pairwise order) ----
    if (tid < BN) {
        const float* x = &z_lds[tid * ZS];
        zn_l[tid] = pairwise256_sq([&](int i) { return x[i]; });
    }
    __syncthreads();

    const int ng = tid >> 5;  // 0..15 -> row group
    const int tk = tid & 31;  // 0..31 -> code group
    const int r0 = ng * 4;

    float mv[4];
    int mk[4];
#pragma unroll
    for (int i = 0; i < 4; ++i) {
        mv[i] = __builtin_inff();
        mk[i] = 0;
    }

    for (int k0 = 0; k0 < KCODES; k0 += BKC) {
        float acc[4][8];
#pragma unroll
        for (int i = 0; i < 4; ++i)
#pragma unroll
            for (int j = 0; j < 8; ++j) acc[i][j] = 0.0f;

        for (int dc = 0; dc < 4; ++dc) {
            __syncthreads();
            // stage ct[d][code] (transposed) for d in [0,64), code in [0,256)
            {
                int code = tid >> 1;
                int dh = (tid & 1) * 32;
                const float* sp = emb + (size_t)(k0 + code) * DDIM + dc * 64 + dh;
#pragma unroll
                for (int q = 0; q < 8; ++q) {
                    float4 v = *(const float4*)(sp + q * 4);
                    int d = dh + q * 4;
                    ct[(d + 0) * CTS + code] = v.x;
                    ct[(d + 1) * CTS + code] = v.y;
                    ct[(d + 2) * CTS + code] = v.z;
                    ct[(d + 3) * CTS + code] = v.w;
                }
            }
            __syncthreads();

            const float* zb0 = &z_lds[(r0 + 0) * ZS + dc * 64];
            const float* zb1 = &z_lds[(r0 + 1) * ZS + dc * 64];
            const float* zb2 = &z_lds[(r0 + 2) * ZS + dc * 64];
            const float* zb3 = &z_lds[(r0 + 3) * ZS + dc * 64];
            const float* cbA = &ct[tk * 4];
            const float* cbB = &ct[128 + tk * 4];

#pragma unroll
            for (int s = 0; s < 16; ++s) {
                float4 za0 = *(const float4*)(zb0 + s * 4);
                float4 za1 = *(const float4*)(zb1 + s * 4);
                float4 za2 = *(const float4*)(zb2 + s * 4);
                float4 za3 = *(const float4*)(zb3 + s * 4);
#pragma unroll
                for (int l = 0; l < 4; ++l) {  // d ascending: outermost over d within step
                    float4 cA = *(const float4*)(cbA + (s * 4 + l) * CTS);
                    float4 cB = *(const float4*)(cbB + (s * 4 + l) * CTS);
                    float zl[4] = {elem4(za0, l), elem4(za1, l), elem4(za2, l), elem4(za3, l)};
#pragma unroll
                    for (int i = 0; i < 4; ++i) {
#pragma unroll
                        for (int j = 0; j < 4; ++j) {
                            acc[i][j] = __builtin_fmaf(zl[i], elem4(cA, j), acc[i][j]);
                            acc[i][4 + j] = __builtin_fmaf(zl[i], elem4(cB, j), acc[i][4 + j]);
                        }
                    }
                }
            }
        }

        // ---- finalize distances for this k-chunk, lexicographic running min ----
        float zn[4];
#pragma unroll
        for (int i = 0; i < 4; ++i) zn[i] = zn_l[r0 + i];
#pragma unroll
        for (int j = 0; j < 8; ++j) {
            int kk = k0 + ((j < 4) ? (tk * 4 + j) : (128 + tk * 4 + (j - 4)));
            float c = cn_l[kk];
#pragma unroll
            for (int i = 0; i < 4; ++i) {
                float t1 = zn[i] + c;             // fl(z_norm + c_norm)
                float dv = t1 - 2.0f * acc[i][j]; // fl(t1 - 2*dot); contraction-safe (2*acc exact)
                if (dv < mv[i] || (dv == mv[i] && kk < mk[i])) {
                    mv[i] = dv;
                    mk[i] = kk;
                }
            }
        }
    }

    // ---- cross-thread argmin per row (lex min over (value, index)) ----
    __syncthreads();
    float* red_v = ct;                       // [64][33]
    int* red_k = (int*)(ct + 64 * 33);       // [64][33]
#pragma unroll
    for (int i = 0; i < 4; ++i) {
        red_v[(r0 + i) * 33 + tk] = mv[i];
        red_k[(r0 + i) * 33 + tk] = mk[i];
    }
    __syncthreads();
    if (tid < BN) {
        float bv = red_v[tid * 33];
        int bk = red_k[tid * 33];
        for (int t = 1; t < 32; ++t) {
            float v = red_v[tid * 33 + t];
            int k = red_k[tid * 33 + t];
            if (v < bv || (v == bv && k < bk)) {
                bv = v;
                bk = k;
            }
        }
        winner[tid] = bk;
        out_idx[row0 + tid] = (float)bk;
    }
    __syncthreads();

    // ---- epilogue: z_q_st = fl(z + fl(zq - z)); loss partial ----
    double lsum = 0.0;
    {
        int row = tid >> 3;
        int seg = (tid & 7) * 32;
        int kk = winner[row];
        const float* zq = emb + (size_t)kk * DDIM + seg;
        const float* zz = &z_lds[row * ZS + seg];
        float4* dst = (float4*)(out_zq + (row0 + row) * DDIM + seg);
#pragma unroll
        for (int q = 0; q < 8; ++q) {
            float4 a = *(const float4*)(zq + q * 4);
            float4 b = *(const float4*)(zz + q * 4);
            float s0 = a.x - b.x, s1 = a.y - b.y, s2 = a.z - b.z, s3 = a.w - b.w;
            float4 o;
            o.x = b.x + s0;
            o.y = b.y + s1;
            o.z = b.z + s2;
            o.w = b.w + s3;
            dst[q] = o;
            float q0 = s0 * s0, q1 = s1 * s1, q2 = s2 * s2, q3 = s3 * s3;
            lsum += (double)q0 + (double)q1 + (double)q2 + (double)q3;
        }
    }
#pragma unroll
    for (int off = 32; off > 0; off >>= 1) lsum += __shfl_down(lsum, off);
    if ((tid & 63) == 0) wsum[tid >> 6] = lsum;
    __syncthreads();
    if (tid == 0) {
        double t = 0.0;
#pragma unroll
        for (int w = 0; w < 8; ++w) t += wsum[w];
        ws_part[bid] = t;
    }
}

__global__ void loss_k(const double* __restrict__ part, float* __restrict__ out_loss) {
    __shared__ double wsum[8];
    int tid = threadIdx.x;
    double s = 0.0;
    for (int i = tid; i < NBLK; i += 512) s += part[i];
#pragma unroll
    for (int off = 32; off > 0; off >>= 1) s += __shfl_down(s, off);
    if ((tid & 63) == 0) wsum[tid >> 6] = s;
    __syncthreads();
    if (tid == 0) {
        double t = 0.0;
#pragma unroll
        for (int w = 0; w < 8; ++w) t += wsum[w];
        out_loss[0] = (float)(COMMIT * (t / ((double)NROWS * (double)DDIM)));
    }
}

extern "C" void kernel_launch(void* const* d_in, const int* in_sizes, int n_in,
                              void* d_out, int out_size, void* d_ws, size_t ws_size,
                              hipStream_t stream) {
    const float* z_e = (const float*)d_in[0];
    const float* emb = (const float*)d_in[1];
    float* out = (float*)d_out;
    float* out_zq = out;
    float* out_idx = out + (size_t)NROWS * DDIM;
    float* out_loss = out_idx + NROWS;

    double* part = (double*)d_ws;                                   // 2048 doubles
    float* cn_g = (float*)((char*)d_ws + NBLK * sizeof(double));    // 1024 floats

    cnorm_k<<<4, 256, 0, stream>>>(emb, cn_g);
    vq_main<<<NBLK, 512, 0, stream>>>(z_e, emb, cn_g, out_zq, out_idx, part);
    loss_k<<<1, 512, 0, stream>>>(part, out_loss);
}